// Round 9
// baseline (377.617 us; speedup 1.0000x reference)
//
#include <hip/hip_runtime.h>
#include <hip/hip_bf16.h>
#include <hip/hip_cooperative_groups.h>

namespace cg = cooperative_groups;

// y = softmax((xWq+bq)(xWk+bk)^T / 8) (xWv+bv), per head, NO causal mask.
// B=2,S=2048,D=1024,H=16,hd=64. Dtype sniffed (fp32 vs bf16).
// Cooperative fused kernel: ph0 X->bf16 (d_out) | ph1 K,V^T GEMMs (ws)
// | ph2a per-block Q-tile GEMM -> regs | ph2b flash attention -> d_out.

#define D_MODEL 1024
#define NHEAD   16
#define HDIM    64
#define SEQ     2048

typedef __attribute__((ext_vector_type(8))) short short8;
typedef __attribute__((ext_vector_type(4))) float f32x4;

__device__ __forceinline__ float bf2f(unsigned short u) {
  return __uint_as_float(((unsigned int)u) << 16);
}
__device__ __forceinline__ unsigned short f2bf(float f) {
  unsigned int u = __float_as_uint(f);
  u += 0x7fff + ((u >> 16) & 1);
  return (unsigned short)(u >> 16);
}
__device__ __forceinline__ unsigned pk2(float a, float b) {
  union { __hip_bfloat162 h; unsigned u; } cv;
  cv.h = __float22bfloat162_rn(make_float2(a, b));
  return cv.u;
}
__device__ __forceinline__ int sniff_bf16(const unsigned short* x) {
  const int lane = threadIdx.x & 63;
  const unsigned e = (x[2 * lane] >> 7) & 0xFF;
  unsigned long long m = __ballot(e >= 105 && e <= 140);
  return __popcll(m) >= 48;
}
// XOR swizzle for unpadded [row][64] bf16 tiles (8-elem k-blocks)
__device__ __forceinline__ int swz(int row, int k8) {
  return ((k8 ^ (row & 7) ^ ((row >> 3) & 7)) << 3);
}

#define CSC 0.18033688011112042f   // log2(e)/sqrt(64)

__global__ __launch_bounds__(256, 2) void fused(
    const unsigned short* __restrict__ X,
    const unsigned short* __restrict__ Wq, const unsigned short* __restrict__ Wk,
    const unsigned short* __restrict__ Wv,
    const unsigned short* __restrict__ bq, const unsigned short* __restrict__ bk,
    const unsigned short* __restrict__ bv,
    unsigned short* __restrict__ Xbf,     // = d_out
    unsigned short* __restrict__ K, unsigned short* __restrict__ Vt,
    unsigned short* __restrict__ Outg) {  // = d_out
  __shared__ alignas(16) unsigned char pool[43008];
  cg::grid_group grid = cg::this_grid();

  const int bid  = blockIdx.x;
  const int tid  = threadIdx.x;
  const int wave = tid >> 6, lane = tid & 63;
  const int lrow = lane & 15, lk = lane >> 4;
  const int isbf = sniff_bf16(X);

  // ---------------- phase 0: X -> bf16 into Xbf (d_out) ----------------
  {
    const size_t base   = ((size_t)bid * 256 + tid) * 8;
    const size_t stride = (size_t)512 * 256 * 8;
#pragma unroll
    for (int i = 0; i < 4; ++i) {
      const size_t idx = base + (size_t)i * stride;
      if (isbf) {
        *(uint4*)(Xbf + idx) = *(const uint4*)(X + idx);
      } else {
        const float* Xf = (const float*)X;
        const float4 f0 = *(const float4*)(Xf + idx);
        const float4 f1 = *(const float4*)(Xf + idx + 4);
        uint4 t = {pk2(f0.x, f0.y), pk2(f0.z, f0.w), pk2(f1.x, f1.y), pk2(f1.z, f1.w)};
        *(uint4*)(Xbf + idx) = t;
      }
    }
  }
  grid.sync();

  // ---------------- phase 1: K (prescaled) and V^T GEMMs ----------------
  {
    unsigned short* As = (unsigned short*)pool;             // [128][64] swz
    unsigned short* Bs = (unsigned short*)(pool + 16384);   // [128][64] swz
    const int part = bid >> 8;           // 0: K, 1: V
    const int lid = bid & 255;
    const int nb = lid & 7, mb = lid >> 3;
    const unsigned short* W    = part ? Wv : Wk;
    const unsigned short* bias = part ? bv : bk;
    const int isbfw = sniff_bf16(W);
    const int m0 = mb * 128, n0 = nb * 128;
    const int wm = wave >> 1, wn = wave & 1;
    const int kg = tid >> 4, ng = tid & 15;

    f32x4 acc[4][4] = {};
    for (int kk = 0; kk < D_MODEL; kk += 64) {
#pragma unroll
      for (int i = 0; i < 4; ++i) {
        const int c = i * 256 + tid;
        const int mrow = c >> 3, k8 = c & 7;
        *(uint4*)(&As[mrow * 64 + swz(mrow, k8)]) =
            *(const uint4*)(Xbf + (size_t)(m0 + mrow) * D_MODEL + kk + k8 * 8);
      }
      {
        const int k8 = kg >> 1, klo = (kg & 1) * 4;
        if (isbfw) {
          unsigned short el[4][8];
#pragma unroll
          for (int t = 0; t < 4; ++t) {
            uint4 v = *(const uint4*)(W + (size_t)(kk + kg * 4 + t) * D_MODEL + n0 + ng * 8);
            const unsigned short* e = (const unsigned short*)&v;
#pragma unroll
            for (int j = 0; j < 8; ++j) el[t][j] = e[j];
          }
#pragma unroll
          for (int j = 0; j < 8; ++j) {
            const int n = ng * 8 + j;
            ushort4 w4 = {el[0][j], el[1][j], el[2][j], el[3][j]};
            *(ushort4*)(&Bs[n * 64 + swz(n, k8) + klo]) = w4;
          }
        } else {
          float el[4][8];
#pragma unroll
          for (int t = 0; t < 4; ++t) {
            const float* Wf = (const float*)W + (size_t)(kk + kg * 4 + t) * D_MODEL + n0 + ng * 8;
            const float4 f0 = *(const float4*)Wf;
            const float4 f1 = *(const float4*)(Wf + 4);
            el[t][0] = f0.x; el[t][1] = f0.y; el[t][2] = f0.z; el[t][3] = f0.w;
            el[t][4] = f1.x; el[t][5] = f1.y; el[t][6] = f1.z; el[t][7] = f1.w;
          }
#pragma unroll
          for (int j = 0; j < 8; ++j) {
            const int n = ng * 8 + j;
            uint2 w2 = {pk2(el[0][j], el[1][j]), pk2(el[2][j], el[3][j])};
            *(uint2*)(&Bs[n * 64 + swz(n, k8) + klo]) = w2;
          }
        }
      }
      __syncthreads();
#pragma unroll
      for (int ks2 = 0; ks2 < 2; ++ks2) {
        const int k8 = ks2 * 4 + lk;
        short8 a[4], b[4];
#pragma unroll
        for (int t = 0; t < 4; ++t) {
          const int mr = wm * 64 + t * 16 + lrow;
          const int nr = wn * 64 + t * 16 + lrow;
          a[t] = *(const short8*)(&As[mr * 64 + swz(mr, k8)]);
          b[t] = *(const short8*)(&Bs[nr * 64 + swz(nr, k8)]);
        }
#pragma unroll
        for (int mt = 0; mt < 4; ++mt)
#pragma unroll
          for (int nt = 0; nt < 4; ++nt)
            acc[mt][nt] = __builtin_amdgcn_mfma_f32_16x16x32_bf16(a[mt], b[nt], acc[mt][nt], 0, 0, 0);
      }
      __syncthreads();
    }
#pragma unroll
    for (int nt = 0; nt < 4; ++nt) {
      const int col = n0 + wn * 64 + nt * 16 + lrow;
      const float bb = isbfw ? bf2f(bias[col]) : ((const float*)bias)[col];
#pragma unroll
      for (int mt = 0; mt < 4; ++mt) {
        const int row0 = m0 + wm * 64 + mt * 16 + lk * 4;
        if (part == 0) {
#pragma unroll
          for (int r = 0; r < 4; ++r)
            K[(size_t)(row0 + r) * D_MODEL + col] = f2bf((acc[mt][nt][r] + bb) * CSC);
        } else {
          const int b2 = row0 >> 11, s = row0 & 2047;
          const int bh2 = b2 * NHEAD + (col >> 6), d = col & 63;
          uint2 pk = {pk2(acc[mt][nt][0] + bb, acc[mt][nt][1] + bb),
                      pk2(acc[mt][nt][2] + bb, acc[mt][nt][3] + bb)};
          *(uint2*)(Vt + ((size_t)bh2 * HDIM + d) * SEQ + s) = pk;
        }
      }
    }
  }
  grid.sync();

  // ---------------- phase 2a: per-block Q-tile GEMM -> qf regs ----------------
  const int bh = bid & 31, qt = bid >> 5;     // XCD = bh%8: K/V L2-local
  const int b = bh >> 4, h = bh & 15;
  short8 qf[2][2];
  {
    unsigned short* As2 = (unsigned short*)pool;             // [128][64] swz
    unsigned short* Bs2 = (unsigned short*)(pool + 16384);   // [64][64] swz
    unsigned short* Qs  = (unsigned short*)(pool + 24576);   // [128][72]
    const int isbfq = sniff_bf16(Wq);
    const int R0 = b * SEQ + qt * 128;
    const int ng = tid & 7, kg = tid >> 3;    // kg 0..31 = k-pair idx
    f32x4 acc[2][4] = {};
    for (int kk = 0; kk < D_MODEL; kk += 64) {
#pragma unroll
      for (int i = 0; i < 4; ++i) {
        const int c = i * 256 + tid;
        const int mrow = c >> 3, k8 = c & 7;
        *(uint4*)(&As2[mrow * 64 + swz(mrow, k8)]) =
            *(const uint4*)(Xbf + (size_t)(R0 + mrow) * D_MODEL + kk + k8 * 8);
      }
      {
        const int k = kg * 2;
        const int k8 = k >> 3, kin = k & 7;
        if (isbfq) {
          uint4 v0 = *(const uint4*)(Wq + (size_t)(kk + k) * D_MODEL + h * HDIM + ng * 8);
          uint4 v1 = *(const uint4*)(Wq + (size_t)(kk + k + 1) * D_MODEL + h * HDIM + ng * 8);
          const unsigned short* e0 = (const unsigned short*)&v0;
          const unsigned short* e1 = (const unsigned short*)&v1;
#pragma unroll
          for (int j = 0; j < 8; ++j) {
            const int n = ng * 8 + j;
            ushort2 w2 = {e0[j], e1[j]};
            *(ushort2*)(&Bs2[n * 64 + swz(n, k8) + kin]) = w2;
          }
        } else {
          const float* Wf = (const float*)Wq;
          const float4 a0 = *(const float4*)(Wf + (size_t)(kk + k) * D_MODEL + h * HDIM + ng * 8);
          const float4 a1 = *(const float4*)(Wf + (size_t)(kk + k) * D_MODEL + h * HDIM + ng * 8 + 4);
          const float4 c0 = *(const float4*)(Wf + (size_t)(kk + k + 1) * D_MODEL + h * HDIM + ng * 8);
          const float4 c1 = *(const float4*)(Wf + (size_t)(kk + k + 1) * D_MODEL + h * HDIM + ng * 8 + 4);
          const float e0[8] = {a0.x, a0.y, a0.z, a0.w, a1.x, a1.y, a1.z, a1.w};
          const float e1[8] = {c0.x, c0.y, c0.z, c0.w, c1.x, c1.y, c1.z, c1.w};
#pragma unroll
          for (int j = 0; j < 8; ++j) {
            const int n = ng * 8 + j;
            *(unsigned*)(&Bs2[n * 64 + swz(n, k8) + kin]) = pk2(e0[j], e1[j]);
          }
        }
      }
      __syncthreads();
#pragma unroll
      for (int ks2 = 0; ks2 < 2; ++ks2) {
        const int k8 = ks2 * 4 + lk;
        short8 a[2], bfr[4];
#pragma unroll
        for (int mq = 0; mq < 2; ++mq) {
          const int mr = wave * 32 + mq * 16 + lrow;
          a[mq] = *(const short8*)(&As2[mr * 64 + swz(mr, k8)]);
        }
#pragma unroll
        for (int nd = 0; nd < 4; ++nd) {
          const int nr = nd * 16 + lrow;
          bfr[nd] = *(const short8*)(&Bs2[nr * 64 + swz(nr, k8)]);
        }
#pragma unroll
        for (int mq = 0; mq < 2; ++mq)
#pragma unroll
          for (int nd = 0; nd < 4; ++nd)
            acc[mq][nd] = __builtin_amdgcn_mfma_f32_16x16x32_bf16(a[mq], bfr[nd], acc[mq][nd], 0, 0, 0);
      }
      __syncthreads();
    }
    // Q tile (+bias) -> Qs [q][d], then extract B-operand frags
#pragma unroll
    for (int nd = 0; nd < 4; ++nd) {
      const int d = nd * 16 + lrow;
      const float bb = isbfq ? bf2f(bq[h * HDIM + d]) : ((const float*)bq)[h * HDIM + d];
#pragma unroll
      for (int mq = 0; mq < 2; ++mq) {
        const int q = wave * 32 + mq * 16 + lk * 4;
#pragma unroll
        for (int r = 0; r < 4; ++r)
          Qs[(q + r) * 72 + d] = f2bf(acc[mq][nd][r] + bb);
      }
    }
    __syncthreads();
#pragma unroll
    for (int nq = 0; nq < 2; ++nq)
#pragma unroll
      for (int ks = 0; ks < 2; ++ks)
        qf[nq][ks] = *(const short8*)(&Qs[(wave * 32 + nq * 16 + lrow) * 72 + ks * 32 + lk * 8]);
  }
  grid.sync();

  // ---------------- phase 2b: attention (round-5 proven structure) ----------------
  {
    unsigned short* Ks = (unsigned short*)pool;            // [64][72]
    unsigned short* Vs = (unsigned short*)(pool + 9216);   // [64][72]
    unsigned short* Ps = (unsigned short*)(pool + 18432);  // [128][72]
    const size_t baseR = (size_t)b * SEQ * D_MODEL + h * HDIM;
    const size_t baseV = (size_t)bh * HDIM * SEQ;
    const int q0 = qt * 128, wq = wave * 32;
    f32x4 accO[2][4] = {};
    float lsum[2] = {0.f, 0.f};

    for (int kv0 = 0; kv0 < SEQ; kv0 += 64) {
      __syncthreads();
#pragma unroll
      for (int i = 0; i < 2; ++i) {
        const int c = tid + i * 256;
        const int row = c >> 3, off = (c & 7) * 8;
        *(uint4*)(&Ks[row * 72 + off]) =
            *(const uint4*)(K + baseR + (size_t)(kv0 + row) * D_MODEL + off);
        *(uint4*)(&Vs[row * 72 + off]) =
            *(const uint4*)(Vt + baseV + (size_t)row * SEQ + kv0 + off);
      }
      __syncthreads();

      f32x4 accST[4][2] = {};
#pragma unroll
      for (int ks = 0; ks < 2; ++ks) {
        short8 kf[4];
#pragma unroll
        for (int mt = 0; mt < 4; ++mt)
          kf[mt] = *(const short8*)(&Ks[(mt * 16 + lrow) * 72 + ks * 32 + lk * 8]);
#pragma unroll
        for (int mt = 0; mt < 4; ++mt)
#pragma unroll
          for (int nq = 0; nq < 2; ++nq)
            accST[mt][nq] = __builtin_amdgcn_mfma_f32_16x16x32_bf16(
                kf[mt], qf[nq][ks], accST[mt][nq], 0, 0, 0);
      }
#pragma unroll
      for (int mt = 0; mt < 4; ++mt)
#pragma unroll
        for (int nq = 0; nq < 2; ++nq) {
          const float p0 = exp2f(accST[mt][nq][0]), p1 = exp2f(accST[mt][nq][1]);
          const float p2 = exp2f(accST[mt][nq][2]), p3 = exp2f(accST[mt][nq][3]);
          lsum[nq] += (p0 + p1) + (p2 + p3);
          uint2 pk = {pk2(p0, p1), pk2(p2, p3)};
          *(uint2*)(&Ps[(wq + nq * 16 + lrow) * 72 + mt * 16 + lk * 4]) = pk;
        }
#pragma unroll
      for (int ks = 0; ks < 2; ++ks) {
        short8 pf[2], vf[4];
#pragma unroll
        for (int mq = 0; mq < 2; ++mq)
          pf[mq] = *(const short8*)(&Ps[(wq + mq * 16 + lrow) * 72 + ks * 32 + lk * 8]);
#pragma unroll
        for (int nd = 0; nd < 4; ++nd)
          vf[nd] = *(const short8*)(&Vs[(nd * 16 + lrow) * 72 + ks * 32 + lk * 8]);
#pragma unroll
        for (int mq = 0; mq < 2; ++mq)
#pragma unroll
          for (int nd = 0; nd < 4; ++nd)
            accO[mq][nd] = __builtin_amdgcn_mfma_f32_16x16x32_bf16(
                pf[mq], vf[nd], accO[mq][nd], 0, 0, 0);
      }
    }
#pragma unroll
    for (int nq = 0; nq < 2; ++nq) {
      lsum[nq] += __shfl_xor(lsum[nq], 16, 64);
      lsum[nq] += __shfl_xor(lsum[nq], 32, 64);
    }
    __syncthreads();
    float* Lf = (float*)Ps;
    if (lk == 0) { Lf[wq + lrow] = lsum[0]; Lf[wq + 16 + lrow] = lsum[1]; }
#pragma unroll
    for (int mq = 0; mq < 2; ++mq) {
      const f32x4 l4 = *(const f32x4*)(&Lf[wq + mq * 16 + lk * 4]);
#pragma unroll
      for (int r = 0; r < 4; ++r) {
        const float inv = 1.0f / l4[r];
        const int row = q0 + wq + mq * 16 + lk * 4 + r;
#pragma unroll
        for (int nd = 0; nd < 4; ++nd) {
          const int col = h * HDIM + nd * 16 + lrow;
          const float val = accO[mq][nd][r] * inv;
          const size_t idx = (size_t)b * SEQ * D_MODEL + (size_t)row * D_MODEL + col;
          if (isbf) Outg[idx] = f2bf(val);
          else      ((float*)Outg)[idx] = val;
        }
      }
    }
  }
}

// ================= fallback (non-coop) pair: r8 qkv + r5 attn ===============
#define LDA 40
__global__ __launch_bounds__(256) void qkv_fb(
    const unsigned short* __restrict__ X,
    const unsigned short* __restrict__ Wq, const unsigned short* __restrict__ Wk,
    const unsigned short* __restrict__ Wv,
    const unsigned short* __restrict__ bq, const unsigned short* __restrict__ bk,
    const unsigned short* __restrict__ bv,
    unsigned short* __restrict__ Q, unsigned short* __restrict__ K,
    unsigned short* __restrict__ Vt) {
  const int z = blockIdx.z;
  const unsigned short* W    = (z == 0) ? Wq : ((z == 1) ? Wv : Wk);
  const unsigned short* bias = (z == 0) ? bq : ((z == 1) ? bv : bk);
  __shared__ unsigned short As[128 * 64];
  __shared__ unsigned short Bs[128 * 64];
  const int isbf = sniff_bf16(X);
  const int tid = threadIdx.x;
  const int wave = tid >> 6, lane = tid & 63;
  const int wm = wave >> 1, wn = wave & 1;
  const int lrow = lane & 15, lk = lane >> 4;
  const int m0 = blockIdx.y * 128, n0 = blockIdx.x * 128;
  const int kg = tid >> 4, ng = tid & 15;
  f32x4 acc[4][4] = {};
  for (int kk = 0; kk < D_MODEL; kk += 64) {
#pragma unroll
    for (int i = 0; i < 4; ++i) {
      const int c = i * 256 + tid;
      const int mrow = c >> 3, k8 = c & 7;
      unsigned short* dst = &As[mrow * 64 + swz(mrow, k8)];
      if (isbf) {
        *(uint4*)dst = *(const uint4*)(X + (size_t)(m0 + mrow) * D_MODEL + kk + k8 * 8);
      } else {
        const float* Xf = (const float*)X + (size_t)(m0 + mrow) * D_MODEL + kk + k8 * 8;
        const float4 f0 = *(const float4*)Xf;
        const float4 f1 = *(const float4*)(Xf + 4);
        uint4 t = {pk2(f0.x, f0.y), pk2(f0.z, f0.w), pk2(f1.x, f1.y), pk2(f1.z, f1.w)};
        *(uint4*)dst = t;
      }
    }
    {
      const int k8 = kg >> 1, klo = (kg & 1) * 4;
      if (isbf) {
        unsigned short el[4][8];
#pragma unroll
        for (int t = 0; t < 4; ++t) {
          uint4 v = *(const uint4*)(W + (size_t)(kk + kg * 4 + t) * D_MODEL + n0 + ng * 8);
          const unsigned short* e = (const unsigned short*)&v;
#pragma unroll
          for (int j = 0; j < 8; ++j) el[t][j] = e[j];
        }
#pragma unroll
        for (int j = 0; j < 8; ++j) {
          const int n = ng * 8 + j;
          ushort4 w4 = {el[0][j], el[1][j], el[2][j], el[3][j]};
          *(ushort4*)(&Bs[n * 64 + swz(n, k8) + klo]) = w4;
        }
      } else {
        float el[4][8];
#pragma unroll
        for (int t = 0; t < 4; ++t) {
          const float* Wf = (const float*)W + (size_t)(kk + kg * 4 + t) * D_MODEL + n0 + ng * 8;
          const float4 f0 = *(const float4*)Wf;
          const float4 f1 = *(const float4*)(Wf + 4);
          el[t][0] = f0.x; el[t][1] = f0.y; el[t][2] = f0.z; el[t][3] = f0.w;
          el[t][4] = f1.x; el[t][5] = f1.y; el[t][6] = f1.z; el[t][7] = f1.w;
        }
#pragma unroll
        for (int j = 0; j < 8; ++j) {
          const int n = ng * 8 + j;
          uint2 w2 = {pk2(el[0][j], el[1][j]), pk2(el[2][j], el[3][j])};
          *(uint2*)(&Bs[n * 64 + swz(n, k8) + klo]) = w2;
        }
      }
    }
    __syncthreads();
#pragma unroll
    for (int ks2 = 0; ks2 < 2; ++ks2) {
      const int k8 = ks2 * 4 + lk;
      short8 a[4], bfr[4];
#pragma unroll
      for (int t = 0; t < 4; ++t) {
        const int mr = wm * 64 + t * 16 + lrow;
        const int nr = wn * 64 + t * 16 + lrow;
        a[t]   = *(const short8*)(&As[mr * 64 + swz(mr, k8)]);
        bfr[t] = *(const short8*)(&Bs[nr * 64 + swz(nr, k8)]);
      }
#pragma unroll
      for (int mt = 0; mt < 4; ++mt)
#pragma unroll
        for (int nt = 0; nt < 4; ++nt)
          acc[mt][nt] = __builtin_amdgcn_mfma_f32_16x16x32_bf16(a[mt], bfr[nt], acc[mt][nt], 0, 0, 0);
    }
    __syncthreads();
  }
#pragma unroll
  for (int nt = 0; nt < 4; ++nt) {
    const int col = n0 + wn * 64 + nt * 16 + lrow;
    const float bb = isbf ? bf2f(bias[col]) : ((const float*)bias)[col];
#pragma unroll
    for (int mt = 0; mt < 4; ++mt) {
      const int row0 = m0 + wm * 64 + mt * 16 + lk * 4;
      if (z == 0) {
#pragma unroll
        for (int r = 0; r < 4; ++r)
          Q[(size_t)(row0 + r) * D_MODEL + col] = f2bf(acc[mt][nt][r] + bb);
      } else if (z == 1) {
        const int b2 = row0 >> 11, s = row0 & 2047;
        const int bh2 = b2 * NHEAD + (col >> 6), d = col & 63;
        uint2 pk = {pk2(acc[mt][nt][0] + bb, acc[mt][nt][1] + bb),
                    pk2(acc[mt][nt][2] + bb, acc[mt][nt][3] + bb)};
        *(uint2*)(Vt + ((size_t)bh2 * HDIM + d) * SEQ + s) = pk;
      } else {
#pragma unroll
        for (int r = 0; r < 4; ++r)
          K[(size_t)(row0 + r) * D_MODEL + col] = f2bf((acc[mt][nt][r] + bb) * CSC);
      }
    }
  }
}

__global__ __launch_bounds__(256) void attn_fb(
    const unsigned short* __restrict__ Qg, const unsigned short* __restrict__ Kg,
    const unsigned short* __restrict__ Vtg, unsigned short* __restrict__ Outg,
    const unsigned short* __restrict__ Xs) {
  const int bh = blockIdx.x, qt = blockIdx.y;
  const int b = bh >> 4, h = bh & 15;
  const size_t baseR = (size_t)b * SEQ * D_MODEL + h * HDIM;
  const size_t baseV = (size_t)bh * HDIM * SEQ;
  __shared__ alignas(16) unsigned short Ks[64 * 72];
  __shared__ alignas(16) unsigned short Vs[64 * 72];
  __shared__ alignas(16) unsigned short Ps[128 * 72];
  const int isbf = sniff_bf16(Xs);
  const int tid = threadIdx.x;
  const int wave = tid >> 6, lane = tid & 63;
  const int lrow = lane & 15, lk = lane >> 4;
  const int q0 = qt * 128, wq = wave * 32;
  short8 qf[2][2];
#pragma unroll
  for (int nq = 0; nq < 2; ++nq)
#pragma unroll
    for (int ks = 0; ks < 2; ++ks)
      qf[nq][ks] = *(const short8*)(Qg + baseR +
          (size_t)(q0 + wq + nq * 16 + lrow) * D_MODEL + ks * 32 + lk * 8);
  f32x4 accO[2][4] = {};
  float lsum[2] = {0.f, 0.f};
  for (int kv0 = 0; kv0 < SEQ; kv0 += 64) {
    __syncthreads();
#pragma unroll
    for (int i = 0; i < 2; ++i) {
      const int c = tid + i * 256;
      const int row = c >> 3, off = (c & 7) * 8;
      *(uint4*)(&Ks[row * 72 + off]) =
          *(const uint4*)(Kg + baseR + (size_t)(kv0 + row) * D_MODEL + off);
      *(uint4*)(&Vs[row * 72 + off]) =
          *(const uint4*)(Vtg + baseV + (size_t)row * SEQ + kv0 + off);
    }
    __syncthreads();
    f32x4 accST[4][2] = {};
#pragma unroll
    for (int ks = 0; ks < 2; ++ks) {
      short8 kf[4];
#pragma unroll
      for (int mt = 0; mt < 4; ++mt)
        kf[mt] = *(const short8*)(&Ks[(mt * 16 + lrow) * 72 + ks * 32 + lk * 8]);
#pragma unroll
      for (int mt = 0; mt < 4; ++mt)
#pragma unroll
        for (int nq = 0; nq < 2; ++nq)
          accST[mt][nq] = __builtin_amdgcn_mfma_f32_16x16x32_bf16(
              kf[mt], qf[nq][ks], accST[mt][nq], 0, 0, 0);
    }
#pragma unroll
    for (int mt = 0; mt < 4; ++mt)
#pragma unroll
      for (int nq = 0; nq < 2; ++nq) {
        const float p0 = exp2f(accST[mt][nq][0]), p1 = exp2f(accST[mt][nq][1]);
        const float p2 = exp2f(accST[mt][nq][2]), p3 = exp2f(accST[mt][nq][3]);
        lsum[nq] += (p0 + p1) + (p2 + p3);
        uint2 pk = {pk2(p0, p1), pk2(p2, p3)};
        *(uint2*)(&Ps[(wq + nq * 16 + lrow) * 72 + mt * 16 + lk * 4]) = pk;
      }
#pragma unroll
    for (int ks = 0; ks < 2; ++ks) {
      short8 pf[2], vf[4];
#pragma unroll
      for (int mq = 0; mq < 2; ++mq)
        pf[mq] = *(const short8*)(&Ps[(wq + mq * 16 + lrow) * 72 + ks * 32 + lk * 8]);
#pragma unroll
      for (int nd = 0; nd < 4; ++nd)
        vf[nd] = *(const short8*)(&Vs[(nd * 16 + lrow) * 72 + ks * 32 + lk * 8]);
#pragma unroll
      for (int mq = 0; mq < 2; ++mq)
#pragma unroll
        for (int nd = 0; nd < 4; ++nd)
          accO[mq][nd] = __builtin_amdgcn_mfma_f32_16x16x32_bf16(
              pf[mq], vf[nd], accO[mq][nd], 0, 0, 0);
    }
  }
#pragma unroll
  for (int nq = 0; nq < 2; ++nq) {
    lsum[nq] += __shfl_xor(lsum[nq], 16, 64);
    lsum[nq] += __shfl_xor(lsum[nq], 32, 64);
  }
  __syncthreads();
  float* Lf = (float*)Ps;
  if (lk == 0) { Lf[wq + lrow] = lsum[0]; Lf[wq + 16 + lrow] = lsum[1]; }
#pragma unroll
  for (int mq = 0; mq < 2; ++mq) {
    const f32x4 l4 = *(const f32x4*)(&Lf[wq + mq * 16 + lk * 4]);
#pragma unroll
    for (int r = 0; r < 4; ++r) {
      const float inv = 1.0f / l4[r];
      const int row = q0 + wq + mq * 16 + lk * 4 + r;
#pragma unroll
      for (int nd = 0; nd < 4; ++nd) {
        const int col = h * HDIM + nd * 16 + lrow;
        const float val = accO[mq][nd][r] * inv;
        const size_t idx = (size_t)b * SEQ * D_MODEL + (size_t)row * D_MODEL + col;
        if (isbf) Outg[idx] = f2bf(val);
        else      ((float*)Outg)[idx] = val;
      }
    }
  }
}

extern "C" void kernel_launch(void* const* d_in, const int* in_sizes, int n_in,
                              void* d_out, int out_size, void* d_ws, size_t ws_size,
                              hipStream_t stream) {
  const unsigned short* x  = (const unsigned short*)d_in[0];
  const unsigned short* Wq = (const unsigned short*)d_in[1];
  const unsigned short* bq = (const unsigned short*)d_in[2];
  const unsigned short* Wk = (const unsigned short*)d_in[3];
  const unsigned short* bk = (const unsigned short*)d_in[4];
  const unsigned short* Wv = (const unsigned short*)d_in[5];
  const unsigned short* bv = (const unsigned short*)d_in[6];
  unsigned short* out = (unsigned short*)d_out;
  unsigned short* ws  = (unsigned short*)d_ws;

  unsigned short* Vt = ws;                 // [0, 4M) els
  unsigned short* K  = ws + (4u << 20);    // [4M, 8M) els

  void* args[] = {(void*)&x, (void*)&Wq, (void*)&Wk, (void*)&Wv,
                  (void*)&bq, (void*)&bk, (void*)&bv,
                  (void*)&out, (void*)&K, (void*)&Vt, (void*)&out};
  hipError_t e = hipLaunchCooperativeKernel((void*)fused, dim3(512), dim3(256),
                                            args, 0, stream);
  if (e != hipSuccess) {
    // non-cooperative fallback (proven r8 + r5 structures)
    qkv_fb<<<dim3(8, 32, 3), 256, 0, stream>>>(x, Wq, Wk, Wv, bq, bk, bv, out, K, Vt);
    attn_fb<<<dim3(32, 16), 256, 0, stream>>>(out, K, Vt, out, x);
  }
}